// Round 1
// baseline (104.718 us; speedup 1.0000x reference)
//
#include <hip/hip_runtime.h>

#define NN 4096
#define MM 4096
#define NEG 0.01f

// 256 threads = 4 waves per block; each wave computes one row of W.
// Grid = NN/4 = 1024 blocks -> 4 blocks/CU on 256 CUs.
__global__ __launch_bounds__(256, 4) void abstract_leaky_relu_kernel(
    const float* __restrict__ lbnd,
    const float* __restrict__ ubnd,
    const float* __restrict__ alpha,
    const float* __restrict__ W,
    const float* __restrict__ b,
    const float* __restrict__ l0,
    const float* __restrict__ u0,
    float* __restrict__ out)
{
    __shared__ float s_c[MM];  // center of input box
    __shared__ float s_r[MM];  // radius of input box

    // Cooperative stage of c,r into LDS (coalesced, computed on the fly).
    for (int j = threadIdx.x; j < MM; j += 256) {
        float l = l0[j], u = u0[j];
        s_c[j] = 0.5f * (l + u);
        s_r[j] = 0.5f * (u - l);
    }
    __syncthreads();

    const int wave = threadIdx.x >> 6;
    const int lane = threadIdx.x & 63;
    const int row  = (blockIdx.x << 2) + wave;

    const float* __restrict__ Wr = W + (size_t)row * MM;

    float s1 = 0.0f;  // W . c
    float s2 = 0.0f;  // |W| . r
    // 64 lanes * 16 B = 1 KiB per iteration; 16 iterations over the row.
    #pragma unroll 4
    for (int j = lane * 4; j < MM; j += 64 * 4) {
        const float4 w = *(const float4*)(Wr + j);
        const float4 c = *(const float4*)(s_c + j);
        const float4 r = *(const float4*)(s_r + j);
        s1 += w.x * c.x + w.y * c.y + w.z * c.z + w.w * c.w;
        s2 += fabsf(w.x) * r.x + fabsf(w.y) * r.y +
              fabsf(w.z) * r.z + fabsf(w.w) * r.w;
    }

    // Wave-level butterfly reduction across 64 lanes.
    #pragma unroll
    for (int off = 32; off > 0; off >>= 1) {
        s1 += __shfl_down(s1, off);
        s2 += __shfl_down(s2, off);
    }

    if (lane == 0) {
        const float L = lbnd[row];
        const float U = ubnd[row];
        const float A = alpha[row];
        const float B = b[row];

        float lw = NEG, uw = NEG, ub_bias = 0.0f;
        if (L > 0.0f) {
            lw = 1.0f; uw = 1.0f;
        } else if (L < 0.0f && U > 0.0f) {
            const float slope = (U - NEG * L) / (U - L);
            uw = slope;
            ub_bias = (NEG - slope) * L;
            lw = fminf(fmaxf(A, NEG), 1.0f);
        }

        const float Pu = s1 + s2;   // max(W,0)@u0 + min(W,0)@l0
        const float Pl = s1 - s2;   // max(W,0)@l0 + min(W,0)@u0
        out[row]      = lw * (Pl + B);   // lower
        out[NN + row] = uw * (Pu + B);   // upper
    }
}

extern "C" void kernel_launch(void* const* d_in, const int* in_sizes, int n_in,
                              void* d_out, int out_size, void* d_ws, size_t ws_size,
                              hipStream_t stream) {
    const float* lbnd  = (const float*)d_in[0];
    const float* ubnd  = (const float*)d_in[1];
    const float* alpha = (const float*)d_in[2];
    const float* W     = (const float*)d_in[3];
    const float* b     = (const float*)d_in[4];
    const float* l0    = (const float*)d_in[5];
    const float* u0    = (const float*)d_in[6];
    float* out = (float*)d_out;

    abstract_leaky_relu_kernel<<<NN / 4, 256, 0, stream>>>(
        lbnd, ubnd, alpha, W, b, l0, u0, out);
}